// Round 2
// baseline (456.427 us; speedup 1.0000x reference)
//
#include <hip/hip_runtime.h>

using f16   = _Float16;
using f16x8 = _Float16 __attribute__((ext_vector_type(8)));
using f16x4 = _Float16 __attribute__((ext_vector_type(4)));
using f32x4 = float    __attribute__((ext_vector_type(4)));

constexpr int BM = 128, BN = 128, BK = 64;
constexpr int KD = 1024, ND = 1024;

// element offset of (row r, k-chunk c[0..7]) in a [rows][BK] f16 tile,
// XOR-swizzled so stride-BK*2B column reads are bank-conflict-free.
__device__ __forceinline__ int swz(int r, int c) {
  return r * BK + ((c ^ (r & 7)) << 3);
}

// ---------------- weight transpose + cast: W[k][n] fp32 -> Wt[n][k] f16 ----
__global__ __launch_bounds__(256)
void wtrans_k(const float* __restrict__ W, f16* __restrict__ Wt) {
  __shared__ float tile[32][33];
  int bx = blockIdx.x * 32;  // n block
  int by = blockIdx.y * 32;  // k block
  int tx = threadIdx.x, ty = threadIdx.y;
#pragma unroll
  for (int i = 0; i < 4; ++i) {
    int r = ty + i * 8;
    tile[r][tx] = W[(size_t)(by + r) * ND + bx + tx];
  }
  __syncthreads();
#pragma unroll
  for (int i = 0; i < 4; ++i) {
    int r = ty + i * 8;
    Wt[(size_t)(bx + r) * KD + by + tx] = (f16)tile[tx][r];
  }
}

// ---------------- GEMM: C = A(fp32,[M,1024]) * Bt(f16,[1024,1024])^T -------
// MODE 0: C f16 [m][n], scaled.       (Q-proj scale=0.125, K-proj scale=1)
// MODE 1: C f16 V-transposed per head: C[((bg*16+h)*64+e)*1024 + kv]
// MODE 2: C fp32 final output remap:   C[((b*512+lq)*4+g)*1024 + n]
template <int MODE>
__global__ __launch_bounds__(256)
void gemm_k(const float* __restrict__ A, const f16* __restrict__ Bt,
            void* __restrict__ C, float scale) {
  __shared__ __attribute__((aligned(16))) f16 As[BM * BK];
  __shared__ __attribute__((aligned(16))) f16 Bs[BN * BK];
  const int t = threadIdx.x;
  const int w = t >> 6, l = t & 63, l15 = l & 15, lg = l >> 4;
  const int m0 = blockIdx.y * BM, n0 = blockIdx.x * BN;
  const int wm = (w >> 1) * 64, wn = (w & 1) * 64;

  f32x4 acc[4][4] = {};

  for (int kb = 0; kb < KD; kb += BK) {
    // stage A: fp32 -> f16, 128x64 tile, 2 rounds, 16 floats/thread/round
#pragma unroll
    for (int rr = 0; rr < 2; ++rr) {
      int idx = rr * 256 + t;
      int r = idx >> 2, q = idx & 3;
      const f32x4* src = (const f32x4*)(A + (size_t)(m0 + r) * KD + kb + q * 16);
      f16 bv[16];
#pragma unroll
      for (int i = 0; i < 4; ++i) {
        f32x4 x = src[i];
        bv[i * 4 + 0] = (f16)x[0]; bv[i * 4 + 1] = (f16)x[1];
        bv[i * 4 + 2] = (f16)x[2]; bv[i * 4 + 3] = (f16)x[3];
      }
      int c0 = q * 2;
      *(f16x8*)&As[swz(r, c0)]     = *(f16x8*)&bv[0];
      *(f16x8*)&As[swz(r, c0 + 1)] = *(f16x8*)&bv[8];
    }
    // stage B: f16 [128 n-rows][64 k] = 1024 x8-stores -> FOUR rounds.
    // (was 2 rounds: rows 64..127 were never written -> NaN from stale LDS)
#pragma unroll
    for (int rr = 0; rr < 4; ++rr) {
      int idx = rr * 256 + t;
      int r = idx >> 3, c = idx & 7;
      f16x8 x = *(const f16x8*)(Bt + (size_t)(n0 + r) * KD + kb + c * 8);
      *(f16x8*)&Bs[swz(r, c)] = x;
    }
    __syncthreads();
#pragma unroll
    for (int ks = 0; ks < 2; ++ks) {
      f16x8 av[4], bw[4];
      int cc = ks * 4 + lg;
#pragma unroll
      for (int mf = 0; mf < 4; ++mf)
        av[mf] = *(const f16x8*)&As[swz(wm + mf * 16 + l15, cc)];
#pragma unroll
      for (int nf = 0; nf < 4; ++nf)
        bw[nf] = *(const f16x8*)&Bs[swz(wn + nf * 16 + l15, cc)];
#pragma unroll
      for (int mf = 0; mf < 4; ++mf)
#pragma unroll
        for (int nf = 0; nf < 4; ++nf)
          acc[mf][nf] = __builtin_amdgcn_mfma_f32_16x16x32_f16(
              av[mf], bw[nf], acc[mf][nf], 0, 0, 0);
    }
    __syncthreads();
  }

  // epilogue: C row = mb + reg (4 consecutive), col = n
#pragma unroll
  for (int mf = 0; mf < 4; ++mf) {
#pragma unroll
    for (int nf = 0; nf < 4; ++nf) {
      int mb = m0 + wm + mf * 16 + 4 * lg;
      int n  = n0 + wn + nf * 16 + l15;
      if (MODE == 0) {
#pragma unroll
        for (int r = 0; r < 4; ++r)
          ((f16*)C)[(size_t)(mb + r) * ND + n] = (f16)(acc[mf][nf][r] * scale);
      } else if (MODE == 1) {
        int bg = mb >> 10, kv = mb & 1023;
        int h = n >> 6, e = n & 63;
        f16x4 pk;
#pragma unroll
        for (int r = 0; r < 4; ++r) pk[r] = (f16)acc[mf][nf][r];
        *(f16x4*)((f16*)C + (size_t)((bg * 16 + h) * 64 + e) * 1024 + kv) = pk;
      } else {
#pragma unroll
        for (int r = 0; r < 4; ++r) {
          int m = mb + r;
          int bg = m >> 9, lq = m & 511;
          int bb = bg >> 2, g = bg & 3;
          ((float*)C)[(size_t)(((bb << 9) + lq) * 4 + g) * 1024 + n] =
              acc[mf][nf][r];
        }
      }
    }
  }
}

// ---------------- flash attention per (b,g,h) --------------------------------
// Qb: f16 [b*512+lq][h*64+d] (pre-scaled), Kb: f16 [bg*1024+kv][h*64+d],
// Vt: f16 [((bg*16+h)*64+e)][kv], ctx out: fp32 [bg*512+lq][h*64+e]
__global__ __launch_bounds__(256)
void attn_k(const f16* __restrict__ Qb, const f16* __restrict__ Kb,
            const f16* __restrict__ Vt, const int* __restrict__ mask,
            float* __restrict__ ctx) {
  __shared__ int smask[1024];
  __shared__ __attribute__((aligned(16))) f16 Ks[64 * 64];
  __shared__ __attribute__((aligned(16))) f16 Vs[64 * 64];
  __shared__ __attribute__((aligned(16))) f16 Pl[4][16 * 72];

  const int t = threadIdx.x, w = t >> 6, l = t & 63, l15 = l & 15, lg = l >> 4;
  const int y = blockIdx.y;
  const int bg = y >> 4, h = y & 15;
  const int bb = bg >> 2;
  const int q0 = blockIdx.x * 64 + w * 16;

  *(int4*)&smask[t * 4] = *(const int4*)(mask + bg * 1024 + t * 4);
  __syncthreads();

  f16x8 aQ[2];
  const f16* qp = Qb + (size_t)(bb * 512 + q0 + l15) * 1024 + h * 64 + lg * 8;
  aQ[0] = *(const f16x8*)qp;
  aQ[1] = *(const f16x8*)(qp + 32);

  float mrow[4], rs[4] = {0.f, 0.f, 0.f, 0.f};
#pragma unroll
  for (int r = 0; r < 4; ++r) mrow[r] = -1e30f;
  f32x4 accO[4] = {};

  const f16* Kbase = Kb + (size_t)bg * 1024 * 1024 + h * 64;
  const f16* Vbase = Vt + (size_t)(bg * 16 + h) * 64 * 1024;

  for (int c16 = 0; c16 < 16; ++c16) {
    const int kv0 = c16 * 64;
    // stage K[64kv][64d] and V^T[64e][64kv] chunks into swizzled LDS
#pragma unroll
    for (int rr = 0; rr < 2; ++rr) {
      int idx = rr * 256 + t;
      int r = idx >> 3, cc = idx & 7;
      f16x8 kx = *(const f16x8*)(Kbase + (size_t)(kv0 + r) * 1024 + cc * 8);
      *(f16x8*)&Ks[swz(r, cc)] = kx;
      f16x8 vx = *(const f16x8*)(Vbase + (size_t)r * 1024 + kv0 + cc * 8);
      *(f16x8*)&Vs[swz(r, cc)] = vx;
    }
    __syncthreads();

    // S = Q K^T  (C: row=q=4*lg+reg, col=kv=nf*16+l15)
    f32x4 s[4] = {};
#pragma unroll
    for (int nf = 0; nf < 4; ++nf) {
      int kr = nf * 16 + l15;
      f16x8 k0 = *(const f16x8*)&Ks[swz(kr, lg)];
      f16x8 k1 = *(const f16x8*)&Ks[swz(kr, 4 + lg)];
      s[nf] = __builtin_amdgcn_mfma_f32_16x16x32_f16(aQ[0], k0, s[nf], 0, 0, 0);
      s[nf] = __builtin_amdgcn_mfma_f32_16x16x32_f16(aQ[1], k1, s[nf], 0, 0, 0);
    }
    // mask
#pragma unroll
    for (int nf = 0; nf < 4; ++nf) {
      if (smask[kv0 + nf * 16 + l15] == 0) {
#pragma unroll
        for (int r = 0; r < 4; ++r) s[nf][r] = -1e30f;
      }
    }
    // online softmax per q-row
#pragma unroll
    for (int r = 0; r < 4; ++r) {
      float v = fmaxf(fmaxf(s[0][r], s[1][r]), fmaxf(s[2][r], s[3][r]));
      v = fmaxf(v, __shfl_xor(v, 1));
      v = fmaxf(v, __shfl_xor(v, 2));
      v = fmaxf(v, __shfl_xor(v, 4));
      v = fmaxf(v, __shfl_xor(v, 8));
      float mn = fmaxf(mrow[r], v);
      float sc = __expf(mrow[r] - mn);
      mrow[r] = mn;
      rs[r] *= sc;
#pragma unroll
      for (int nf = 0; nf < 4; ++nf) accO[nf][r] *= sc;
      float ps = 0.f;
#pragma unroll
      for (int nf = 0; nf < 4; ++nf) {
        float p = __expf(s[nf][r] - mn);
        ps += p;
        Pl[w][(4 * lg + r) * 72 + nf * 16 + l15] = (f16)p;
      }
      rs[r] += ps;
    }
    // PV: O += P V   (A: row=q=l15, k=kv; B: col=e=nf*16+l15, k=kv)
#pragma unroll
    for (int ks = 0; ks < 2; ++ks) {
      f16x8 aP = *(const f16x8*)&Pl[w][l15 * 72 + ks * 32 + lg * 8];
#pragma unroll
      for (int nf = 0; nf < 4; ++nf) {
        f16x8 bV = *(const f16x8*)&Vs[swz(nf * 16 + l15, ks * 4 + lg)];
        accO[nf] = __builtin_amdgcn_mfma_f32_16x16x32_f16(aP, bV, accO[nf], 0, 0, 0);
      }
    }
    __syncthreads();
  }

  // finalize: divide by row sums, write fp32 ctx
#pragma unroll
  for (int r = 0; r < 4; ++r) {
    float v = rs[r];
    v += __shfl_xor(v, 1);
    v += __shfl_xor(v, 2);
    v += __shfl_xor(v, 4);
    v += __shfl_xor(v, 8);
    rs[r] = 1.0f / v;
  }
#pragma unroll
  for (int nf = 0; nf < 4; ++nf)
#pragma unroll
    for (int r = 0; r < 4; ++r) {
      int q = q0 + 4 * lg + r;
      ctx[(size_t)(bg * 512 + q) * 1024 + h * 64 + nf * 16 + l15] =
          accO[nf][r] * rs[r];
    }
}

// ---------------------------------------------------------------------------
extern "C" void kernel_launch(void* const* d_in, const int* in_sizes, int n_in,
                              void* d_out, int out_size, void* d_ws,
                              size_t ws_size, hipStream_t stream) {
  const float* H  = (const float*)d_in[0];
  const float* KV = (const float*)d_in[1];
  const int*  msk = (const int*)d_in[2];
  const float* Wq = (const float*)d_in[3];
  const float* Wk = (const float*)d_in[4];
  const float* Wv = (const float*)d_in[5];
  const float* Wo = (const float*)d_in[6];

  char* ws = (char*)d_ws;
  f16* WqT = (f16*)(ws + (size_t)0);          // 2 MB
  f16* WkT = (f16*)(ws + ((size_t)2 << 20));  // 2 MB
  f16* WvT = (f16*)(ws + ((size_t)4 << 20));  // 2 MB
  f16* WoT = (f16*)(ws + ((size_t)6 << 20));  // 2 MB
  f16* Qb  = (f16*)(ws + ((size_t)8 << 20));  // 4 MB   [2048][1024]
  f16* Kb  = (f16*)(ws + ((size_t)12 << 20)); // 32 MB  [16384][1024]
  f16* Vtb = (f16*)(ws + ((size_t)44 << 20)); // 32 MB  [16*16*64][1024]
  float* ctx = (float*)(ws + ((size_t)76 << 20)); // 32 MB [8192][1024] fp32

  dim3 tb32(32, 8);
  wtrans_k<<<dim3(32, 32), tb32, 0, stream>>>(Wq, WqT);
  wtrans_k<<<dim3(32, 32), tb32, 0, stream>>>(Wk, WkT);
  wtrans_k<<<dim3(32, 32), tb32, 0, stream>>>(Wv, WvT);
  wtrans_k<<<dim3(32, 32), tb32, 0, stream>>>(Wo, WoT);

  gemm_k<0><<<dim3(8, 16),  256, 0, stream>>>(H,  WqT, (void*)Qb,  0.125f);
  gemm_k<0><<<dim3(8, 128), 256, 0, stream>>>(KV, WkT, (void*)Kb,  1.0f);
  gemm_k<1><<<dim3(8, 128), 256, 0, stream>>>(KV, WvT, (void*)Vtb, 1.0f);

  attn_k<<<dim3(8, 256), 256, 0, stream>>>(Qb, Kb, Vtb, msk, ctx);

  gemm_k<2><<<dim3(8, 64), 256, 0, stream>>>(ctx, WoT, d_out, 1.0f);
}

// Round 4
// 403.886 us; speedup vs baseline: 1.1301x; 1.1301x over previous
//
#include <hip/hip_runtime.h>

using f16   = _Float16;
using f16x8 = _Float16 __attribute__((ext_vector_type(8)));
using f16x4 = _Float16 __attribute__((ext_vector_type(4)));
using f32x4 = float    __attribute__((ext_vector_type(4)));

constexpr int BM = 128, BN = 128, BK = 64;
constexpr int KD = 1024, ND = 1024;

// element offset of (row r, k-chunk c[0..7]) in a [rows][BK] f16 tile,
// XOR-swizzled so stride-BK*2B column reads are bank-conflict-free.
__device__ __forceinline__ int swz(int r, int c) {
  return r * BK + ((c ^ (r & 7)) << 3);
}

// async global->LDS, 16B per lane; LDS dest is wave-uniform base + lane*16.
__device__ __forceinline__ void gload_lds16(const f16* g, f16* s) {
  __builtin_amdgcn_global_load_lds(
      (const __attribute__((address_space(1))) void*)g,
      (__attribute__((address_space(3))) void*)s, 16, 0, 0);
}

// ---------------- fp32 -> f16 cast, 8 elems/thread --------------------------
__global__ __launch_bounds__(256)
void cast_k(const float* __restrict__ in, f16* __restrict__ out) {
  size_t i = ((size_t)blockIdx.x * 256 + threadIdx.x) * 8;
  f32x4 a = *(const f32x4*)(in + i);
  f32x4 b = *(const f32x4*)(in + i + 4);
  f16x8 o;
  o[0] = (f16)a[0]; o[1] = (f16)a[1]; o[2] = (f16)a[2]; o[3] = (f16)a[3];
  o[4] = (f16)b[0]; o[5] = (f16)b[1]; o[6] = (f16)b[2]; o[7] = (f16)b[3];
  *(f16x8*)(out + i) = o;
}

// ---------------- weight transpose + cast: W[k][n] fp32 -> Wt[n][k] f16 ----
__global__ __launch_bounds__(256)
void wtrans_k(const float* __restrict__ W, f16* __restrict__ Wt) {
  __shared__ float tile[32][33];
  int bx = blockIdx.x * 32;  // n block
  int by = blockIdx.y * 32;  // k block
  int tx = threadIdx.x, ty = threadIdx.y;
#pragma unroll
  for (int i = 0; i < 4; ++i) {
    int r = ty + i * 8;
    tile[r][tx] = W[(size_t)(by + r) * ND + bx + tx];
  }
  __syncthreads();
#pragma unroll
  for (int i = 0; i < 4; ++i) {
    int r = ty + i * 8;
    Wt[(size_t)(bx + r) * KD + by + tx] = (f16)tile[tx][r];
  }
}

// ---------------- GEMM: C = A(f16,[M,1024]) * Bt(f16,[1024,1024])^T --------
// Both operands staged via global_load_lds (16B/lane); the XOR swizzle is
// applied on the per-lane GLOBAL source column so LDS content matches swz().
// MODE 0: C f16 [m][n], scaled.       (Q-proj scale=0.125, K-proj scale=1)
// MODE 1: C f16 V-transposed per head: C[((bg*16+h)*64+e)*1024 + kv]
// MODE 2: C fp32 final output remap:   C[((b*512+lq)*4+g)*1024 + n]
template <int MODE>
__global__ __launch_bounds__(256)
void gemm_k(const f16* __restrict__ A, const f16* __restrict__ Bt,
            void* __restrict__ C, float scale) {
  __shared__ __attribute__((aligned(16))) f16 As[BM * BK];
  __shared__ __attribute__((aligned(16))) f16 Bs[BN * BK];
  const int t = threadIdx.x;
  const int w = t >> 6, l = t & 63, l15 = l & 15, lg = l >> 4;
  const int m0 = blockIdx.y * BM, n0 = blockIdx.x * BN;
  const int wm = (w >> 1) * 64, wn = (w & 1) * 64;
  const int lr  = l >> 3;                  // row-within-8 for staging
  const int csw = ((l & 7) ^ lr) << 3;     // pre-swizzled source chunk (f16)

  const f16* Ab = A  + (size_t)m0 * KD + csw;
  const f16* Bb = Bt + (size_t)n0 * KD + csw;

  f32x4 acc[4][4] = {};

  for (int kb = 0; kb < KD; kb += BK) {
#pragma unroll
    for (int i = 0; i < 4; ++i) {
      int ii = w * 4 + i;          // 16 issues of 8 rows each
      int r  = ii * 8 + lr;
      gload_lds16(Ab + (size_t)r * KD + kb, &As[ii * 512]);
      gload_lds16(Bb + (size_t)r * KD + kb, &Bs[ii * 512]);
    }
    __syncthreads();
#pragma unroll
    for (int ks = 0; ks < 2; ++ks) {
      f16x8 av[4], bw[4];
      int cc = ks * 4 + lg;
#pragma unroll
      for (int mf = 0; mf < 4; ++mf)
        av[mf] = *(const f16x8*)&As[swz(wm + mf * 16 + l15, cc)];
#pragma unroll
      for (int nf = 0; nf < 4; ++nf)
        bw[nf] = *(const f16x8*)&Bs[swz(wn + nf * 16 + l15, cc)];
#pragma unroll
      for (int mf = 0; mf < 4; ++mf)
#pragma unroll
        for (int nf = 0; nf < 4; ++nf)
          acc[mf][nf] = __builtin_amdgcn_mfma_f32_16x16x32_f16(
              av[mf], bw[nf], acc[mf][nf], 0, 0, 0);
    }
    __syncthreads();
  }

  // epilogue: C row = mb + reg (4 consecutive), col = n
#pragma unroll
  for (int mf = 0; mf < 4; ++mf) {
#pragma unroll
    for (int nf = 0; nf < 4; ++nf) {
      int mb = m0 + wm + mf * 16 + 4 * lg;
      int n  = n0 + wn + nf * 16 + l15;
      if (MODE == 0) {
#pragma unroll
        for (int r = 0; r < 4; ++r)
          ((f16*)C)[(size_t)(mb + r) * ND + n] = (f16)(acc[mf][nf][r] * scale);
      } else if (MODE == 1) {
        int bg = mb >> 10, kv = mb & 1023;
        int h = n >> 6, e = n & 63;
        f16x4 pk;
#pragma unroll
        for (int r = 0; r < 4; ++r) pk[r] = (f16)acc[mf][nf][r];
        *(f16x4*)((f16*)C + (size_t)((bg * 16 + h) * 64 + e) * 1024 + kv) = pk;
      } else {
#pragma unroll
        for (int r = 0; r < 4; ++r) {
          int m = mb + r;
          int bg = m >> 9, lq = m & 511;
          int bb = bg >> 2, g = bg & 3;
          ((float*)C)[(size_t)(((bb << 9) + lq) * 4 + g) * 1024 + n] =
              acc[mf][nf][r];
        }
      }
    }
  }
}

// ---------------- flash attention per (b,g,h) --------------------------------
// Qb: f16 [b*512+lq][h*64+d] (pre-scaled), Kb: f16 [bg*1024+kv][h*64+d],
// Vt: f16 [((bg*16+h)*64+e)][kv], ctx out: f16 [bg*512+lq][h*64+e]
// 4 waves x 32 q-rows = 128 q-rows/block; K/V staged via global_load_lds.
__global__ __launch_bounds__(256)
void attn_k(const f16* __restrict__ Qb, const f16* __restrict__ Kb,
            const f16* __restrict__ Vt, const int* __restrict__ mask,
            f16* __restrict__ ctx) {
  __shared__ int smask[1024];
  __shared__ __attribute__((aligned(16))) f16 Ks[64 * 64];
  __shared__ __attribute__((aligned(16))) f16 Vs[64 * 64];
  __shared__ __attribute__((aligned(16))) f16 Pl[4][32 * 72];

  const int t = threadIdx.x, w = t >> 6, l = t & 63, l15 = l & 15, lg = l >> 4;
  const int y = blockIdx.y, bg = y >> 4, h = y & 15, bb = bg >> 2;
  const int q0 = blockIdx.x * 128 + w * 32;
  const int lr = l >> 3, csw = ((l & 7) ^ lr) << 3;

  *(int4*)&smask[t * 4] = *(const int4*)(mask + bg * 1024 + t * 4);

  f16x8 aQ[2][2];
#pragma unroll
  for (int mf = 0; mf < 2; ++mf) {
    const f16* qp =
        Qb + (size_t)(bb * 512 + q0 + mf * 16 + l15) * 1024 + h * 64 + lg * 8;
    aQ[mf][0] = *(const f16x8*)qp;
    aQ[mf][1] = *(const f16x8*)(qp + 32);
  }

  float mrow[2][4], rs[2][4];
#pragma unroll
  for (int mf = 0; mf < 2; ++mf)
#pragma unroll
    for (int r = 0; r < 4; ++r) { mrow[mf][r] = -1e30f; rs[mf][r] = 0.f; }
  f32x4 accO[2][4] = {};

  const f16* Kbase = Kb + (size_t)bg * (1024 * 1024) + h * 64 + csw;
  const f16* Vbase = Vt + (size_t)(bg * 16 + h) * (64 * 1024) + csw;

  __syncthreads();  // smask visible

  for (int c16 = 0; c16 < 16; ++c16) {
    const int kv0 = c16 * 64;
#pragma unroll
    for (int i = 0; i < 2; ++i) {
      int ii = w * 2 + i;
      int r  = ii * 8 + lr;
      gload_lds16(Kbase + (size_t)(kv0 + r) * 1024, &Ks[ii * 512]);
      gload_lds16(Vbase + (size_t)r * 1024 + kv0,   &Vs[ii * 512]);
    }
    __syncthreads();

    // S = Q K^T  (per mf: row=q=4*lg+r, col=kv=nf*16+l15)
    f32x4 s[2][4] = {};
#pragma unroll
    for (int nf = 0; nf < 4; ++nf) {
      int kr = nf * 16 + l15;
      f16x8 k0 = *(const f16x8*)&Ks[swz(kr, lg)];
      f16x8 k1 = *(const f16x8*)&Ks[swz(kr, 4 + lg)];
#pragma unroll
      for (int mf = 0; mf < 2; ++mf) {
        s[mf][nf] = __builtin_amdgcn_mfma_f32_16x16x32_f16(aQ[mf][0], k0, s[mf][nf], 0, 0, 0);
        s[mf][nf] = __builtin_amdgcn_mfma_f32_16x16x32_f16(aQ[mf][1], k1, s[mf][nf], 0, 0, 0);
      }
    }
    // mask
#pragma unroll
    for (int nf = 0; nf < 4; ++nf) {
      if (smask[kv0 + nf * 16 + l15] == 0) {
#pragma unroll
        for (int mf = 0; mf < 2; ++mf)
#pragma unroll
          for (int r = 0; r < 4; ++r) s[mf][nf][r] = -1e30f;
      }
    }
    // online softmax per q-row
#pragma unroll
    for (int mf = 0; mf < 2; ++mf)
#pragma unroll
      for (int r = 0; r < 4; ++r) {
        float v = fmaxf(fmaxf(s[mf][0][r], s[mf][1][r]),
                        fmaxf(s[mf][2][r], s[mf][3][r]));
        v = fmaxf(v, __shfl_xor(v, 1));
        v = fmaxf(v, __shfl_xor(v, 2));
        v = fmaxf(v, __shfl_xor(v, 4));
        v = fmaxf(v, __shfl_xor(v, 8));
        float mn = fmaxf(mrow[mf][r], v);
        float sc = __expf(mrow[mf][r] - mn);
        mrow[mf][r] = mn;
        rs[mf][r] *= sc;
#pragma unroll
        for (int nf = 0; nf < 4; ++nf) accO[mf][nf][r] *= sc;
        float ps = 0.f;
#pragma unroll
        for (int nf = 0; nf < 4; ++nf) {
          float p = __expf(s[mf][nf][r] - mn);
          ps += p;
          Pl[w][(mf * 16 + 4 * lg + r) * 72 + nf * 16 + l15] = (f16)p;
        }
        rs[mf][r] += ps;
      }
    // PV: O += P V   (A: row=q=l15, k=kv; B: col=e=nf*16+l15, k=kv)
#pragma unroll
    for (int ks = 0; ks < 2; ++ks) {
      f16x8 aP[2];
#pragma unroll
      for (int mf = 0; mf < 2; ++mf)
        aP[mf] = *(const f16x8*)&Pl[w][(mf * 16 + l15) * 72 + ks * 32 + lg * 8];
#pragma unroll
      for (int nf = 0; nf < 4; ++nf) {
        f16x8 bV = *(const f16x8*)&Vs[swz(nf * 16 + l15, ks * 4 + lg)];
#pragma unroll
        for (int mf = 0; mf < 2; ++mf)
          accO[mf][nf] = __builtin_amdgcn_mfma_f32_16x16x32_f16(aP[mf], bV, accO[mf][nf], 0, 0, 0);
      }
    }
    __syncthreads();
  }

  // finalize: divide by row sums, write f16 ctx
#pragma unroll
  for (int mf = 0; mf < 2; ++mf)
#pragma unroll
    for (int r = 0; r < 4; ++r) {
      float v = rs[mf][r];
      v += __shfl_xor(v, 1);
      v += __shfl_xor(v, 2);
      v += __shfl_xor(v, 4);
      v += __shfl_xor(v, 8);
      rs[mf][r] = 1.0f / v;
    }
#pragma unroll
  for (int mf = 0; mf < 2; ++mf)
#pragma unroll
    for (int nf = 0; nf < 4; ++nf)
#pragma unroll
      for (int r = 0; r < 4; ++r) {
        int q = q0 + mf * 16 + 4 * lg + r;
        ctx[(size_t)(bg * 512 + q) * 1024 + h * 64 + nf * 16 + l15] =
            (f16)(accO[mf][nf][r] * rs[mf][r]);
      }
}

// ---------------------------------------------------------------------------
extern "C" void kernel_launch(void* const* d_in, const int* in_sizes, int n_in,
                              void* d_out, int out_size, void* d_ws,
                              size_t ws_size, hipStream_t stream) {
  const float* H  = (const float*)d_in[0];
  const float* KV = (const float*)d_in[1];
  const int*  msk = (const int*)d_in[2];
  const float* Wq = (const float*)d_in[3];
  const float* Wk = (const float*)d_in[4];
  const float* Wv = (const float*)d_in[5];
  const float* Wo = (const float*)d_in[6];

  char* ws = (char*)d_ws;
  f16* WqT  = (f16*)(ws + ((size_t)0  << 20));  // 2 MB
  f16* WkT  = (f16*)(ws + ((size_t)2  << 20));  // 2 MB
  f16* WvT  = (f16*)(ws + ((size_t)4  << 20));  // 2 MB
  f16* WoT  = (f16*)(ws + ((size_t)6  << 20));  // 2 MB
  f16* Hf   = (f16*)(ws + ((size_t)8  << 20));  // 4 MB   [2048][1024]
  f16* KVf  = (f16*)(ws + ((size_t)12 << 20));  // 32 MB  [16384][1024] (dead after K/V-proj)
  f16* Qb   = (f16*)(ws + ((size_t)12 << 20));  // 4 MB   alias (written after K/V-proj)
  f16* ctxf = (f16*)(ws + ((size_t)16 << 20));  // 16 MB  [8192][1024]
  f16* Kb   = (f16*)(ws + ((size_t)44 << 20));  // 32 MB
  f16* Vtb  = (f16*)(ws + ((size_t)76 << 20));  // 32 MB  -> total 108 MB

  cast_k<<<1024, 256, 0, stream>>>(H,  Hf);    // 2M elems
  cast_k<<<8192, 256, 0, stream>>>(KV, KVf);   // 16M elems

  dim3 tb32(32, 8);
  wtrans_k<<<dim3(32, 32), tb32, 0, stream>>>(Wq, WqT);
  wtrans_k<<<dim3(32, 32), tb32, 0, stream>>>(Wk, WkT);
  wtrans_k<<<dim3(32, 32), tb32, 0, stream>>>(Wv, WvT);
  wtrans_k<<<dim3(32, 32), tb32, 0, stream>>>(Wo, WoT);

  gemm_k<0><<<dim3(8, 128), 256, 0, stream>>>(KVf, WkT, (void*)Kb,  1.0f);
  gemm_k<1><<<dim3(8, 128), 256, 0, stream>>>(KVf, WvT, (void*)Vtb, 1.0f);
  gemm_k<0><<<dim3(8, 16),  256, 0, stream>>>(Hf,  WqT, (void*)Qb,  0.125f);

  attn_k<<<dim3(4, 256), 256, 0, stream>>>(Qb, Kb, Vtb, msk, ctxf);

  gemm_k<2><<<dim3(8, 64), 256, 0, stream>>>(ctxf, WoT, d_out, 1.0f);
}

// Round 5
// 386.217 us; speedup vs baseline: 1.1818x; 1.0457x over previous
//
#include <hip/hip_runtime.h>

using f16   = _Float16;
using f16x8 = _Float16 __attribute__((ext_vector_type(8)));
using f16x4 = _Float16 __attribute__((ext_vector_type(4)));
using f32x4 = float    __attribute__((ext_vector_type(4)));

constexpr int BM = 128, BN = 128, BK = 64;
constexpr int KD = 1024, ND = 1024;

// element offset of (row r, k-chunk c[0..7]) in a [rows][BK] f16 tile,
// XOR-swizzled so stride-BK*2B column reads are bank-conflict-free.
__device__ __forceinline__ int swz(int r, int c) {
  return r * BK + ((c ^ (r & 7)) << 3);
}

// async global->LDS, 16B per lane; LDS dest is wave-uniform base + lane*16.
__device__ __forceinline__ void gload_lds16(const f16* g, f16* s) {
  __builtin_amdgcn_global_load_lds(
      (const __attribute__((address_space(1))) void*)g,
      (__attribute__((address_space(3))) void*)s, 16, 0, 0);
}

// XCD-chunked bijective blockIdx swizzle (nwg % 8 == 0 for all our grids):
// round-robin hardware dispatch -> each XCD gets a CONTIGUOUS work chunk.
__device__ __forceinline__ int2 xcd_swz() {
  int lin = blockIdx.y * gridDim.x + blockIdx.x;
  int per = (gridDim.x * gridDim.y) >> 3;
  int sw  = (lin & 7) * per + (lin >> 3);
  return make_int2(sw % gridDim.x, sw / gridDim.x);
}

// ---------------- fp32 -> f16 cast, 8 elems/thread --------------------------
__global__ __launch_bounds__(256)
void cast_k(const float* __restrict__ in, f16* __restrict__ out) {
  size_t i = ((size_t)blockIdx.x * 256 + threadIdx.x) * 8;
  f32x4 a = *(const f32x4*)(in + i);
  f32x4 b = *(const f32x4*)(in + i + 4);
  f16x8 o;
  o[0] = (f16)a[0]; o[1] = (f16)a[1]; o[2] = (f16)a[2]; o[3] = (f16)a[3];
  o[4] = (f16)b[0]; o[5] = (f16)b[1]; o[6] = (f16)b[2]; o[7] = (f16)b[3];
  *(f16x8*)(out + i) = o;
}

// ---------------- weight transpose + cast: W[k][n] fp32 -> Wt[n][k] f16 ----
__global__ __launch_bounds__(256)
void wtrans_k(const float* __restrict__ W, f16* __restrict__ Wt) {
  __shared__ float tile[32][33];
  int bx = blockIdx.x * 32;  // n block
  int by = blockIdx.y * 32;  // k block
  int tx = threadIdx.x, ty = threadIdx.y;
#pragma unroll
  for (int i = 0; i < 4; ++i) {
    int r = ty + i * 8;
    tile[r][tx] = W[(size_t)(by + r) * ND + bx + tx];
  }
  __syncthreads();
#pragma unroll
  for (int i = 0; i < 4; ++i) {
    int r = ty + i * 8;
    Wt[(size_t)(bx + r) * KD + by + tx] = (f16)tile[tx][r];
  }
}

// ---------------- GEMM: C = A(f16,[M,1024]) * Bt(f16,[1024,1024])^T --------
// Both operands staged via global_load_lds (16B/lane); the XOR swizzle is
// applied on the per-lane GLOBAL source column so LDS content matches swz().
// MODE 0: C f16 [m][n], scaled.       (Q-proj scale=0.125, K-proj scale=1)
// MODE 1: C f16 V-transposed per head: C[((bg*16+h)*64+e)*1024 + kv]
// MODE 2: C fp32 final output remap:   C[((b*512+lq)*4+g)*1024 + n]
template <int MODE>
__global__ __launch_bounds__(256)
void gemm_k(const f16* __restrict__ A, const f16* __restrict__ Bt,
            void* __restrict__ C, float scale) {
  __shared__ __attribute__((aligned(16))) f16 As[BM * BK];
  __shared__ __attribute__((aligned(16))) f16 Bs[BN * BK];
  const int t = threadIdx.x;
  const int w = t >> 6, l = t & 63, l15 = l & 15, lg = l >> 4;
  const int2 bi = xcd_swz();
  const int m0 = bi.y * BM, n0 = bi.x * BN;
  const int wm = (w >> 1) * 64, wn = (w & 1) * 64;
  const int lr  = l >> 3;                  // row-within-8 for staging
  const int csw = ((l & 7) ^ lr) << 3;     // pre-swizzled source chunk (f16)

  const f16* Ab = A  + (size_t)m0 * KD + csw;
  const f16* Bb = Bt + (size_t)n0 * KD + csw;

  f32x4 acc[4][4] = {};

  for (int kb = 0; kb < KD; kb += BK) {
#pragma unroll
    for (int i = 0; i < 4; ++i) {
      int ii = w * 4 + i;          // 16 issues of 8 rows each
      int r  = ii * 8 + lr;
      gload_lds16(Ab + (size_t)r * KD + kb, &As[ii * 512]);
      gload_lds16(Bb + (size_t)r * KD + kb, &Bs[ii * 512]);
    }
    __syncthreads();
#pragma unroll
    for (int ks = 0; ks < 2; ++ks) {
      f16x8 av[4], bw[4];
      int cc = ks * 4 + lg;
#pragma unroll
      for (int mf = 0; mf < 4; ++mf)
        av[mf] = *(const f16x8*)&As[swz(wm + mf * 16 + l15, cc)];
#pragma unroll
      for (int nf = 0; nf < 4; ++nf)
        bw[nf] = *(const f16x8*)&Bs[swz(wn + nf * 16 + l15, cc)];
#pragma unroll
      for (int mf = 0; mf < 4; ++mf)
#pragma unroll
        for (int nf = 0; nf < 4; ++nf)
          acc[mf][nf] = __builtin_amdgcn_mfma_f32_16x16x32_f16(
              av[mf], bw[nf], acc[mf][nf], 0, 0, 0);
    }
    __syncthreads();
  }

  // epilogue: C row = mb + reg (4 consecutive), col = n
#pragma unroll
  for (int mf = 0; mf < 4; ++mf) {
#pragma unroll
    for (int nf = 0; nf < 4; ++nf) {
      int mb = m0 + wm + mf * 16 + 4 * lg;
      int n  = n0 + wn + nf * 16 + l15;
      if (MODE == 0) {
#pragma unroll
        for (int r = 0; r < 4; ++r)
          ((f16*)C)[(size_t)(mb + r) * ND + n] = (f16)(acc[mf][nf][r] * scale);
      } else if (MODE == 1) {
        int bg = mb >> 10, kv = mb & 1023;
        int h = n >> 6, e = n & 63;
        f16x4 pk;
#pragma unroll
        for (int r = 0; r < 4; ++r) pk[r] = (f16)acc[mf][nf][r];
        *(f16x4*)((f16*)C + (size_t)((bg * 16 + h) * 64 + e) * 1024 + kv) = pk;
      } else {
#pragma unroll
        for (int r = 0; r < 4; ++r) {
          int m = mb + r;
          int bg = m >> 9, lq = m & 511;
          int bb = bg >> 2, g = bg & 3;
          ((float*)C)[(size_t)(((bb << 9) + lq) * 4 + g) * 1024 + n] =
              acc[mf][nf][r];
        }
      }
    }
  }
}

// ---------------- flash attention per (b,g,h) --------------------------------
// Qb: f16 [b*512+lq][h*64+d] (pre-scaled), Kb: f16 [bg*1024+kv][h*64+d],
// Vt: f16 [((bg*16+h)*64+e)][kv], ctx out: f16 [bg*512+lq][h*64+e]
// 4 waves x 32 q-rows; K/V double-buffered via global_load_lds + counted vmcnt.
__global__ __launch_bounds__(256)
void attn_k(const f16* __restrict__ Qb, const f16* __restrict__ Kb,
            const f16* __restrict__ Vt, const int* __restrict__ mask,
            f16* __restrict__ ctx) {
  __shared__ int smask[1024];
  __shared__ __attribute__((aligned(16))) f16 Ks[2][64 * 64];
  __shared__ __attribute__((aligned(16))) f16 Vs[2][64 * 64];
  __shared__ __attribute__((aligned(16))) f16 Pl[4][16 * 72];

  const int t = threadIdx.x, w = t >> 6, l = t & 63, l15 = l & 15, lg = l >> 4;
  const int y = blockIdx.y, bg = y >> 4, h = y & 15, bb = bg >> 2;
  const int q0 = blockIdx.x * 128 + w * 32;
  const int lr = l >> 3, csw = ((l & 7) ^ lr) << 3;

  *(int4*)&smask[t * 4] = *(const int4*)(mask + bg * 1024 + t * 4);

  f16x8 aQ[2][2];
#pragma unroll
  for (int mf = 0; mf < 2; ++mf) {
    const f16* qp =
        Qb + (size_t)(bb * 512 + q0 + mf * 16 + l15) * 1024 + h * 64 + lg * 8;
    aQ[mf][0] = *(const f16x8*)qp;
    aQ[mf][1] = *(const f16x8*)(qp + 32);
  }

  float mrow[2][4], rs[2][4];
#pragma unroll
  for (int mf = 0; mf < 2; ++mf)
#pragma unroll
    for (int r = 0; r < 4; ++r) { mrow[mf][r] = -1e30f; rs[mf][r] = 0.f; }
  f32x4 accO[2][4] = {};

  const f16* Kbase = Kb + (size_t)bg * (1024 * 1024) + h * 64 + csw;
  const f16* Vbase = Vt + (size_t)(bg * 16 + h) * (64 * 1024) + csw;

  // per-wave stage of one 64-kv tile into buffer `buf` (4 loads/wave: K,V,K,V)
  auto stage = [&](int tile, int buf) {
    const int kv0 = tile * 64;
#pragma unroll
    for (int i = 0; i < 2; ++i) {
      int ii = w * 2 + i;
      int r  = ii * 8 + lr;
      gload_lds16(Kbase + (size_t)(kv0 + r) * 1024, &Ks[buf][ii * 512]);
      gload_lds16(Vbase + (size_t)r * 1024 + kv0,   &Vs[buf][ii * 512]);
    }
  };

  __syncthreads();          // smask visible (also drains nothing else yet)
  stage(0, 0);              // prologue: tile 0 -> buf 0

  for (int c16 = 0; c16 < 16; ++c16) {
    const int cur = c16 & 1;
    const int kv0 = c16 * 64;
    if (c16 < 15) {
      stage(c16 + 1, cur ^ 1);                       // prefetch next tile
      asm volatile("s_waitcnt vmcnt(4)" ::: "memory");  // cur tile landed
    } else {
      asm volatile("s_waitcnt vmcnt(0)" ::: "memory");
    }
    __builtin_amdgcn_s_barrier();                    // all waves' cur data in
    __builtin_amdgcn_sched_barrier(0);

    // S = Q K^T  (per mf: row=q=4*lg+r, col=kv=nf*16+l15)
    f32x4 s[2][4] = {};
    __builtin_amdgcn_s_setprio(1);
#pragma unroll
    for (int nf = 0; nf < 4; ++nf) {
      int kr = nf * 16 + l15;
      f16x8 k0 = *(const f16x8*)&Ks[cur][swz(kr, lg)];
      f16x8 k1 = *(const f16x8*)&Ks[cur][swz(kr, 4 + lg)];
#pragma unroll
      for (int mf = 0; mf < 2; ++mf) {
        s[mf][nf] = __builtin_amdgcn_mfma_f32_16x16x32_f16(aQ[mf][0], k0, s[mf][nf], 0, 0, 0);
        s[mf][nf] = __builtin_amdgcn_mfma_f32_16x16x32_f16(aQ[mf][1], k1, s[mf][nf], 0, 0, 0);
      }
    }
    __builtin_amdgcn_s_setprio(0);
    // mask
#pragma unroll
    for (int nf = 0; nf < 4; ++nf) {
      if (smask[kv0 + nf * 16 + l15] == 0) {
#pragma unroll
        for (int mf = 0; mf < 2; ++mf)
#pragma unroll
          for (int r = 0; r < 4; ++r) s[mf][nf][r] = -1e30f;
      }
    }
    // hoist V fragments (shared by both mf halves)
    f16x8 bV[2][4];
#pragma unroll
    for (int ks = 0; ks < 2; ++ks)
#pragma unroll
      for (int nf = 0; nf < 4; ++nf)
        bV[ks][nf] = *(const f16x8*)&Vs[cur][swz(nf * 16 + l15, ks * 4 + lg)];

    // per-mf: online softmax (defer-max THR=8) -> Pl -> PV
#pragma unroll
    for (int mf = 0; mf < 2; ++mf) {
#pragma unroll
      for (int r = 0; r < 4; ++r) {
        float v = fmaxf(fmaxf(s[mf][0][r], s[mf][1][r]),
                        fmaxf(s[mf][2][r], s[mf][3][r]));
        v = fmaxf(v, __shfl_xor(v, 1));
        v = fmaxf(v, __shfl_xor(v, 2));
        v = fmaxf(v, __shfl_xor(v, 4));
        v = fmaxf(v, __shfl_xor(v, 8));
        float mn = mrow[mf][r];
        if (v > mn + 8.f) {          // defer-max: rescale only on real growth
          float sc = __expf(mn - v);
          mn = v; mrow[mf][r] = v;
          rs[mf][r] *= sc;
#pragma unroll
          for (int nf = 0; nf < 4; ++nf) accO[mf][nf][r] *= sc;
        }
        float ps = 0.f;
#pragma unroll
        for (int nf = 0; nf < 4; ++nf) {
          float p = __expf(s[mf][nf][r] - mn);   // bounded by e^8
          ps += p;
          Pl[w][(4 * lg + r) * 72 + nf * 16 + l15] = (f16)p;
        }
        rs[mf][r] += ps;
      }
      // PV: O += P V  (A: row=q=l15, k=kv; B: col=e=nf*16+l15, k=kv)
      __builtin_amdgcn_s_setprio(1);
#pragma unroll
      for (int ks = 0; ks < 2; ++ks) {
        f16x8 aP = *(const f16x8*)&Pl[w][l15 * 72 + ks * 32 + lg * 8];
#pragma unroll
        for (int nf = 0; nf < 4; ++nf)
          accO[mf][nf] = __builtin_amdgcn_mfma_f32_16x16x32_f16(aP, bV[ks][nf], accO[mf][nf], 0, 0, 0);
      }
      __builtin_amdgcn_s_setprio(0);
    }

    // all LDS reads of buf `cur` must COMPLETE before anyone stages into it
    asm volatile("s_waitcnt lgkmcnt(0)" ::: "memory");
    __builtin_amdgcn_s_barrier();
  }

  // finalize: divide by row sums, write f16 ctx
#pragma unroll
  for (int mf = 0; mf < 2; ++mf)
#pragma unroll
    for (int r = 0; r < 4; ++r) {
      float v = rs[mf][r];
      v += __shfl_xor(v, 1);
      v += __shfl_xor(v, 2);
      v += __shfl_xor(v, 4);
      v += __shfl_xor(v, 8);
      rs[mf][r] = 1.0f / v;
    }
#pragma unroll
  for (int mf = 0; mf < 2; ++mf)
#pragma unroll
    for (int nf = 0; nf < 4; ++nf)
#pragma unroll
      for (int r = 0; r < 4; ++r) {
        int q = q0 + mf * 16 + 4 * lg + r;
        ctx[(size_t)(bg * 512 + q) * 1024 + h * 64 + nf * 16 + l15] =
            (f16)(accO[mf][nf][r] * rs[mf][r]);
      }
}

// ---------------------------------------------------------------------------
extern "C" void kernel_launch(void* const* d_in, const int* in_sizes, int n_in,
                              void* d_out, int out_size, void* d_ws,
                              size_t ws_size, hipStream_t stream) {
  const float* H  = (const float*)d_in[0];
  const float* KV = (const float*)d_in[1];
  const int*  msk = (const int*)d_in[2];
  const float* Wq = (const float*)d_in[3];
  const float* Wk = (const float*)d_in[4];
  const float* Wv = (const float*)d_in[5];
  const float* Wo = (const float*)d_in[6];

  char* ws = (char*)d_ws;
  f16* WqT  = (f16*)(ws + ((size_t)0  << 20));  // 2 MB
  f16* WkT  = (f16*)(ws + ((size_t)2  << 20));  // 2 MB
  f16* WvT  = (f16*)(ws + ((size_t)4  << 20));  // 2 MB
  f16* WoT  = (f16*)(ws + ((size_t)6  << 20));  // 2 MB
  f16* Hf   = (f16*)(ws + ((size_t)8  << 20));  // 4 MB   [2048][1024]
  f16* KVf  = (f16*)(ws + ((size_t)12 << 20));  // 32 MB  (dead after K/V-proj)
  f16* Qb   = (f16*)(ws + ((size_t)12 << 20));  // 4 MB   alias (written after K/V-proj)
  f16* ctxf = (f16*)(ws + ((size_t)16 << 20));  // 16 MB  [8192][1024]
  f16* Kb   = (f16*)(ws + ((size_t)44 << 20));  // 32 MB
  f16* Vtb  = (f16*)(ws + ((size_t)76 << 20));  // 32 MB  -> total 108 MB

  cast_k<<<1024, 256, 0, stream>>>(H,  Hf);    // 2M elems
  cast_k<<<8192, 256, 0, stream>>>(KV, KVf);   // 16M elems

  dim3 tb32(32, 8);
  wtrans_k<<<dim3(32, 32), tb32, 0, stream>>>(Wq, WqT);
  wtrans_k<<<dim3(32, 32), tb32, 0, stream>>>(Wk, WkT);
  wtrans_k<<<dim3(32, 32), tb32, 0, stream>>>(Wv, WvT);
  wtrans_k<<<dim3(32, 32), tb32, 0, stream>>>(Wo, WoT);

  gemm_k<0><<<dim3(8, 128), 256, 0, stream>>>(KVf, WkT, (void*)Kb,  1.0f);
  gemm_k<1><<<dim3(8, 128), 256, 0, stream>>>(KVf, WvT, (void*)Vtb, 1.0f);
  gemm_k<0><<<dim3(8, 16),  256, 0, stream>>>(Hf,  WqT, (void*)Qb,  0.125f);

  attn_k<<<dim3(4, 256), 256, 0, stream>>>(Qb, Kb, Vtb, msk, ctxf);

  gemm_k<2><<<dim3(8, 64), 256, 0, stream>>>(ctxf, WoT, d_out, 1.0f);
}